// Round 1
// 93.012 us; speedup vs baseline: 1.0356x; 1.0356x over previous
//
#include <hip/hip_runtime.h>
#include <hip/hip_bf16.h>

// VQ-VAE vector quantizer, MI355X gfx950.
// z: [16,64,64,64] fp32, embed: [1024,64] fp32.
// out: z_q_st [16,64,64,64] fp32, then loss scalar.
//
// R1: bf16-MFMA distances + fused argmin. 46 us main; 1 block/CU -> latency.
// R2: 1024 blocks, 4-wave K-split, no z LDS tile.
// R3: packed (dist|code) u32 argmin -> v_min_u32 everywhere. total 96.3.
// R4 (this round):
//   - z tile staged in LDS ([64][66] fp32 pad -> 2-way max bank alias, free;
//     frag reads become ds_read_b32 w/ immediate offsets, kills ~150
//     instr/wave of scattered global loads + 64-bit address VALU)
//   - K-loop processes tile PAIRS: min(umin, min(uA,uB)) -> v_min3_u32
//     (2.5 VALU/elem instead of 3)
//   - col-reduce via DPP row_shr 1/2/4/8 + v_min_u32 (VALU pipe, no
//     ds_swizzle/lgkmcnt); result at col==15
//   - loss from the packed key: dist = (key-1) + ||z||^2; wave0 accumulates
//     ||z||^2 in fp32 during frag build. Drops the epilogue z re-read
//     (16 scattered loads + 32 VALU/thread). Truncation bias ~1e-6 on loss.

#define K_CODES   1024
#define C_DIM     64
#define HW        4096
#define CHW       262144
#define OUT_ELEMS 4194304
#define LOSS_SCALE (1.25f / 4194304.0f)
#define KEY_MASK  0xFFFFFC00u   // keep exponent + top 13 mantissa bits
#define ZS_PITCH  66            // fp32 row pitch for z LDS tile (pad 64->66)

typedef short v8s __attribute__((ext_vector_type(8)));
typedef float v4f __attribute__((ext_vector_type(4)));

__device__ __forceinline__ unsigned short f2bf(float x) {
  unsigned int u = __float_as_uint(x);
  return (unsigned short)((u + 0x7FFFu + ((u >> 16) & 1u)) >> 16);
}

__device__ __forceinline__ ushort2 f2bf2(float x, float y) {
  union { __hip_bfloat162 h; ushort2 u; } c;
  c.h = __float22bfloat162_rn(make_float2(x, y));
  return c.u;
}

// DPP row_shr:N min-reduce step (old = v keeps invalid lanes at v)
#define DPP_MIN_STEP(v, ctrl)                                                  \
  v = min(v, (unsigned int)__builtin_amdgcn_update_dpp(                        \
                 (int)(v), (int)(v), (ctrl), 0xF, 0xF, false))

// ---------------------------------------------------------------------------
// Setup kernel: 32 blocks x 256 threads (8192 threads).
//  - packs embed into bf16 B-fragment order (see R1-R3 notes).
//  - threads 0..1023: ws_norm[k] = ||embed[k]||^2 + 1.0 (key bias) fp32.
//  - thread 0: zero the loss accumulator.
// ---------------------------------------------------------------------------
__global__ __launch_bounds__(256) void vq_setup(const float* __restrict__ embed,
                                                float* __restrict__ ws_norm,
                                                uint4* __restrict__ ws_frag,
                                                float* __restrict__ out_loss) {
  int id = blockIdx.x * 256 + threadIdx.x;   // 0..8191
  int t   = id >> 7;        // code tile 0..63
  int r   = id & 127;
  int h   = r >> 6;         // k-half 0..1
  int l   = r & 63;         // lane
  int col = l & 15;
  int q   = l >> 4;
  int code = t * 16 + col;
  const float* src = embed + code * C_DIM + h * 32 + q * 8;
  float4 f0 = ((const float4*)src)[0];
  float4 f1 = ((const float4*)src)[1];
  union { unsigned short u[8]; uint4 q4; } pk;
  pk.u[0] = f2bf(f0.x); pk.u[1] = f2bf(f0.y); pk.u[2] = f2bf(f0.z); pk.u[3] = f2bf(f0.w);
  pk.u[4] = f2bf(f1.x); pk.u[5] = f2bf(f1.y); pk.u[6] = f2bf(f1.z); pk.u[7] = f2bf(f1.w);
  ws_frag[id] = pk.q4;

  if (id < K_CODES) {
    const float4* row = (const float4*)(embed + id * C_DIM);
    float s = 0.f;
#pragma unroll
    for (int i = 0; i < 16; ++i) {
      float4 v = row[i];
      s += v.x * v.x + v.y * v.y + v.z * v.z + v.w * v.w;
    }
    ws_norm[id] = s + 1.0f;   // pre-biased: keys = dist_partial + 1 > 0
  }
  if (id == 0) *out_loss = 0.f;
}

// ---------------------------------------------------------------------------
// Main kernel: 1024 blocks x 256 threads (4 waves).
// Block = 64 positions: b = blk>>6, h = blk&63, w = 0..63.
// ---------------------------------------------------------------------------
__global__ __launch_bounds__(256, 4) void vq_main(const float* __restrict__ z,
                                                  const float* __restrict__ embed,
                                                  const float* __restrict__ ws_norm,
                                                  const uint4* __restrict__ ws_frag,
                                                  float* __restrict__ out) {
  __shared__ float zs[64 * ZS_PITCH];   // z tile [c][w], fp32, padded pitch
  __shared__ unsigned int rmin[4][64];
  __shared__ int idx_lds[64];
  __shared__ float znorm_lds[64];

  const int tid  = threadIdx.x;
  const int lane = tid & 63;
  const int wave = tid >> 6;
  const int col  = lane & 15;
  const int q    = lane >> 4;
  const int b    = blockIdx.x >> 6;
  const int h    = blockIdx.x & 63;
  const float* zb = z + b * CHW + h * 64;   // + c*HW + w

  // ---- stage z tile into LDS (coalesced float4 loads, b64 LDS writes) ----
#pragma unroll
  for (int jj = 0; jj < 4; ++jj) {
    const int c = (tid >> 4) + 16 * jj;
    const int w = 4 * (tid & 15);
    float4 v = *(const float4*)(zb + c * HW + w);
    *(float2*)&zs[c * ZS_PITCH + w]     = make_float2(v.x, v.y);
    *(float2*)&zs[c * ZS_PITCH + w + 2] = make_float2(v.z, v.w);
  }
  __syncthreads();

  // ---- build A-frags (z as bf16) from LDS; wave0 also accumulates ||z||^2 --
  // A layout: lane m=lane&15 holds A[m][q*8+j]; hf selects k-half (c += 32).
  v8s afrag[4][2];
  float zn[4] = {0.f, 0.f, 0.f, 0.f};
#pragma unroll
  for (int g = 0; g < 4; ++g) {
    const int w0 = g * 16 + col;
#pragma unroll
    for (int hf = 0; hf < 2; ++hf) {
      const float* src = &zs[(hf * 32 + q * 8) * ZS_PITCH + w0];
      float f[8];
#pragma unroll
      for (int j = 0; j < 8; ++j) f[j] = src[j * ZS_PITCH];
      union { v8s v; ushort2 u2[4]; } pk;
#pragma unroll
      for (int j = 0; j < 4; ++j) pk.u2[j] = f2bf2(f[2 * j], f[2 * j + 1]);
      afrag[g][hf] = pk.v;
      if (wave == 0) {
#pragma unroll
        for (int j = 0; j < 8; ++j) zn[g] = fmaf(f[j], f[j], zn[g]);
      }
    }
  }

  // wave0: finish ||z||^2 per position (sum over q groups) -> LDS
  if (wave == 0) {
#pragma unroll
    for (int g = 0; g < 4; ++g) {
      float s = zn[g];
      s += __shfl_xor(s, 16, 64);
      s += __shfl_xor(s, 32, 64);
      if (q == 0) znorm_lds[g * 16 + col] = s;
    }
  }

  unsigned int umin[4][4];
#pragma unroll
  for (int g = 0; g < 4; ++g)
#pragma unroll
    for (int r = 0; r < 4; ++r) umin[g][r] = 0xFFFFFFFFu;

  // ---- K loop: this wave's 16 code-tiles as 8 PAIRS (v_min3_u32 fuse) ----
  // D layout (verified m89/m91): col = lane&15 (code), row = q*4+reg (pos).
  const int t0 = wave * 16;
#pragma unroll 2
  for (int tp = 0; tp < 8; ++tp) {
    const int t = t0 + 2 * tp;
    uint4 auA0 = ws_frag[t * 128 + lane];            // tile A, k  0..31
    uint4 auA1 = ws_frag[t * 128 + 64 + lane];       // tile A, k 32..63
    uint4 auB0 = ws_frag[(t + 1) * 128 + lane];      // tile B, k  0..31
    uint4 auB1 = ws_frag[(t + 1) * 128 + 64 + lane]; // tile B, k 32..63
    float nrmA = ws_norm[t * 16 + col];              // ||e||^2 + 1
    float nrmB = ws_norm[t * 16 + 16 + col];
    union { uint4 q4; v8s v; } bA0, bA1, bB0, bB1;
    bA0.q4 = auA0; bA1.q4 = auA1; bB0.q4 = auB0; bB1.q4 = auB1;
    const unsigned int codeA = (unsigned int)(t * 16 + col);
    const unsigned int codeB = codeA + 16u;
#pragma unroll
    for (int g = 0; g < 4; ++g) {
      v4f accA = {0.f, 0.f, 0.f, 0.f};
      v4f accB = {0.f, 0.f, 0.f, 0.f};
      accA = __builtin_amdgcn_mfma_f32_16x16x32_bf16(afrag[g][0], bA0.v, accA, 0, 0, 0);
      accA = __builtin_amdgcn_mfma_f32_16x16x32_bf16(afrag[g][1], bA1.v, accA, 0, 0, 0);
      accB = __builtin_amdgcn_mfma_f32_16x16x32_bf16(afrag[g][0], bB0.v, accB, 0, 0, 0);
      accB = __builtin_amdgcn_mfma_f32_16x16x32_bf16(afrag[g][1], bB1.v, accB, 0, 0, 0);
#pragma unroll
      for (int r = 0; r < 4; ++r) {
        float kA = fmaf(-2.f, accA[r], nrmA);        // dist + 1 > 0
        float kB = fmaf(-2.f, accB[r], nrmB);
        unsigned int uA = (__float_as_uint(kA) & KEY_MASK) | codeA;
        unsigned int uB = (__float_as_uint(kB) & KEY_MASK) | codeB;
        umin[g][r] = min(umin[g][r], min(uA, uB));   // -> v_min3_u32
      }
    }
  }

  // ---- reduce across the 16 cols via DPP row_shr (VALU only, no LDS pipe).
  // After the chain, lane col==15 of each 16-lane row holds the row min.
#pragma unroll
  for (int g = 0; g < 4; ++g)
#pragma unroll
    for (int r = 0; r < 4; ++r) {
      unsigned int v = umin[g][r];
      DPP_MIN_STEP(v, 0x111);   // row_shr:1
      DPP_MIN_STEP(v, 0x112);   // row_shr:2
      DPP_MIN_STEP(v, 0x114);   // row_shr:4
      DPP_MIN_STEP(v, 0x118);   // row_shr:8
      umin[g][r] = v;
    }
  if (col == 15) {
#pragma unroll
    for (int g = 0; g < 4; ++g)
#pragma unroll
      for (int r = 0; r < 4; ++r)
        rmin[wave][g * 16 + q * 4 + r] = umin[g][r];
  }
  __syncthreads();

  // ---- merge waves; loss from packed key: dist = (key-1) + ||z||^2 ----
  if (tid < 64) {
    unsigned int bv = min(min(rmin[0][tid], rmin[1][tid]),
                          min(rmin[2][tid], rmin[3][tid]));
    idx_lds[tid] = (int)(bv & 1023u);
    float dist = __uint_as_float(bv & KEY_MASK) - 1.0f + znorm_lds[tid];
#pragma unroll
    for (int off = 32; off >= 1; off >>= 1) dist += __shfl_xor(dist, off, 64);
    if (tid == 0) atomicAdd(out + OUT_ELEMS, dist * LOSS_SCALE);
  }
  __syncthreads();

  // ---- epilogue: z_q scatter (exact fp32 embed rows) ----
  {
    const int w  = tid & 63;
    const int cq = tid >> 6;     // 0..3 -> 16 channels each
    const int idx = idx_lds[w];
    const float4* erow = (const float4*)(embed + idx * C_DIM);
    float* ob = out + b * CHW + h * 64 + w;
#pragma unroll
    for (int j = 0; j < 4; ++j) {
      int c = cq * 16 + j * 4;
      float4 ev = erow[c >> 2];
      ob[(c + 0) * HW] = ev.x;
      ob[(c + 1) * HW] = ev.y;
      ob[(c + 2) * HW] = ev.z;
      ob[(c + 3) * HW] = ev.w;
    }
  }
}

extern "C" void kernel_launch(void* const* d_in, const int* in_sizes, int n_in,
                              void* d_out, int out_size, void* d_ws, size_t ws_size,
                              hipStream_t stream) {
  const float* z     = (const float*)d_in[0];
  const float* embed = (const float*)d_in[1];
  float* out = (float*)d_out;
  // d_ws layout: [0,4096) biased norms fp32 (1024 used), [4096, +131072) bf16 frags
  float* ws_norm = (float*)d_ws;
  uint4* ws_frag = (uint4*)((char*)d_ws + 4096);

  vq_setup<<<32, 256, 0, stream>>>(embed, ws_norm, ws_frag, out + OUT_ELEMS);
  vq_main<<<1024, 256, 0, stream>>>(z, embed, ws_norm, (const uint4*)ws_frag, out);
}